// Round 9
// baseline (327.810 us; speedup 1.0000x reference)
//
#include <hip/hip_runtime.h>

// BoundaryKDV15: per-pixel channel-softmax KL(T||S), masked by class-boundary
// pixels, binned per (batch, class 1..13), normalized, summed to scalar.
//
// V15 vs V11-V14: the per-wave MLP lever is dead -- V11 (2KB/wave in
// flight), V12/V13 (unroll/SW-pipeline), V14 (global_load_lds DMA ring,
// 8KB/wave, literal vmcnt(6)) all deliver ~2.4 TB/s / ~96-107us. V14 also
// broke correctness (absmax 0.03: DMA ring reuse races in-flight ds_reads).
// So: revert to the verified V11 math core (absmax 0.0), and cut the costs
// that haven't been touched:
//   (a) 8 px/thread (1024 blocks): halves boundary/atomic/flush tail and
//       wave count; same 4-loads-per-iter MLP; ~50 live VGPRs, no spill.
//   (b) fuse finalize into the main kernel via device-atomic ticket (last
//       block reduces the 104 bins) -- one fewer launch in the timed graph.
//
// Shapes: preds_S/preds_T [8,14,512,512] f32, gt [8,1,512,512] i32, out: 1 f32.

#define CC 14
#define KB 13          // boundary classes 1..13
#define BB 8
#define HH 512
#define WW 512
#define PP (HH * WW)   // 262144 pixels per image
#define PIX_PER_BLOCK 2048
#define BLOCKS_PER_IMG (PP / PIX_PER_BLOCK)   // 128
#define NBLOCKS (BB * BLOCKS_PER_IMG)         // 1024

// ws layout (floats): [0..103] kl_sum[b][k-1], [104..207] n[b][k-1],
// [208] block-completion ticket (uint bits)
#define NBINS (BB * KB)

__global__ void zero_ws_kernel(float* __restrict__ ws) {
    int i = threadIdx.x;
    if (i < 2 * NBINS + 1) ws[i] = 0.0f;   // 0.0f bit-pattern == uint 0
}

__global__ __launch_bounds__(256) void boundary_kl_kernel(
        const float* __restrict__ S, const float* __restrict__ T,
        const int* __restrict__ gt, float* __restrict__ ws,
        float* __restrict__ out) {
    const int tid = threadIdx.x;
    const int b   = blockIdx.x / BLOCKS_PER_IMG;
    const int base = (blockIdx.x % BLOCKS_PER_IMG) * PIX_PER_BLOCK;
    const int p0  = base + tid * 4;          // pixel group 0
    const int p1  = p0 + 1024;               // pixel group 1 (2 rows below)

    __shared__ float s_kl[KB + 1];
    __shared__ float s_n[KB + 1];
    if (tid <= KB) { s_kl[tid] = 0.0f; s_n[tid] = 0.0f; }
    __syncthreads();

    const float* Sb = S + (size_t)b * CC * PP;
    const float* Tb = T + (size_t)b * CC * PP;
    const int*  gtb = gt + (size_t)b * PP;

    // ---- single-pass softmax-KL accumulation (no max subtraction) ----
    // kl_pix = [sum_c e^{xt}*(xt - xs)] / zT + log zS - log zT
    float4 zS0 = make_float4(0.f,0.f,0.f,0.f), zT0 = zS0, A0 = zS0;
    float4 zS1 = zS0, zT1 = zS0, A1 = zS0;
#pragma unroll 1
    for (int c = 0; c < CC; ++c) {
        const size_t co = (size_t)c * PP;
        const float4 xs0 = *(const float4*)(Sb + co + p0);
        const float4 xt0 = *(const float4*)(Tb + co + p0);
        const float4 xs1 = *(const float4*)(Sb + co + p1);
        const float4 xt1 = *(const float4*)(Tb + co + p1);

        float4 e;
        e = make_float4(__expf(xs0.x), __expf(xs0.y), __expf(xs0.z), __expf(xs0.w));
        zS0.x += e.x; zS0.y += e.y; zS0.z += e.z; zS0.w += e.w;
        e = make_float4(__expf(xt0.x), __expf(xt0.y), __expf(xt0.z), __expf(xt0.w));
        zT0.x += e.x; zT0.y += e.y; zT0.z += e.z; zT0.w += e.w;
        A0.x = fmaf(e.x, xt0.x - xs0.x, A0.x);
        A0.y = fmaf(e.y, xt0.y - xs0.y, A0.y);
        A0.z = fmaf(e.z, xt0.z - xs0.z, A0.z);
        A0.w = fmaf(e.w, xt0.w - xs0.w, A0.w);

        e = make_float4(__expf(xs1.x), __expf(xs1.y), __expf(xs1.z), __expf(xs1.w));
        zS1.x += e.x; zS1.y += e.y; zS1.z += e.z; zS1.w += e.w;
        e = make_float4(__expf(xt1.x), __expf(xt1.y), __expf(xt1.z), __expf(xt1.w));
        zT1.x += e.x; zT1.y += e.y; zT1.z += e.z; zT1.w += e.w;
        A1.x = fmaf(e.x, xt1.x - xs1.x, A1.x);
        A1.y = fmaf(e.y, xt1.y - xs1.y, A1.y);
        A1.z = fmaf(e.z, xt1.z - xs1.z, A1.z);
        A1.w = fmaf(e.w, xt1.w - xs1.w, A1.w);
    }

    float kl0[4], kl1[4];
    kl0[0] = __fdividef(A0.x, zT0.x) + __logf(zS0.x) - __logf(zT0.x);
    kl0[1] = __fdividef(A0.y, zT0.y) + __logf(zS0.y) - __logf(zT0.y);
    kl0[2] = __fdividef(A0.z, zT0.z) + __logf(zS0.z) - __logf(zT0.z);
    kl0[3] = __fdividef(A0.w, zT0.w) + __logf(zS0.w) - __logf(zT0.w);
    kl1[0] = __fdividef(A1.x, zT1.x) + __logf(zS1.x) - __logf(zT1.x);
    kl1[1] = __fdividef(A1.y, zT1.y) + __logf(zS1.y) - __logf(zT1.y);
    kl1[2] = __fdividef(A1.z, zT1.z) + __logf(zS1.z) - __logf(zT1.z);
    kl1[3] = __fdividef(A1.w, zT1.w) + __logf(zS1.w) - __logf(zT1.w);

    // ---- boundary test (cross erosion, zero border => border px are boundary) ----
#define BOUNDARY_BIN(q, kl) do {                                              \
        const int h = (q) >> 9;                                               \
        const int w = (q) & (WW - 1);                                         \
        int4 g = *(const int4*)(gtb + (q));                                   \
        int4 gu = make_int4(-1, -1, -1, -1);                                  \
        int4 gd = make_int4(-1, -1, -1, -1);                                  \
        if (h > 0)      gu = *(const int4*)(gtb + (q) - WW);                  \
        if (h < HH - 1) gd = *(const int4*)(gtb + (q) + WW);                  \
        const int gl = (w > 0)      ? gtb[(q) - 1] : -1;                      \
        const int gr = (w + 4 < WW) ? gtb[(q) + 4] : -1;                      \
        const int gc[4]  = {g.x, g.y, g.z, g.w};                              \
        const int gup[4] = {gu.x, gu.y, gu.z, gu.w};                          \
        const int gdn[4] = {gd.x, gd.y, gd.z, gd.w};                          \
        const int glf[4] = {gl, g.x, g.y, g.z};                               \
        const int grt[4] = {g.y, g.z, g.w, gr};                               \
        _Pragma("unroll")                                                     \
        for (int j = 0; j < 4; ++j) {                                         \
            const int k = gc[j];                                              \
            const bool er = (glf[j] == k) & (grt[j] == k) &                   \
                            (gup[j] == k) & (gdn[j] == k);                    \
            if (k >= 1 && !er) {                                              \
                atomicAdd(&s_kl[k], (kl)[j]);                                 \
                atomicAdd(&s_n[k], 1.0f);                                     \
            }                                                                 \
        }                                                                     \
    } while (0)

    BOUNDARY_BIN(p0, kl0);
    BOUNDARY_BIN(p1, kl1);
#undef BOUNDARY_BIN
    __syncthreads();

    if (tid >= 1 && tid <= KB) {
        atomicAdd(&ws[b * KB + (tid - 1)], s_kl[tid]);
        atomicAdd(&ws[NBINS + b * KB + (tid - 1)], s_n[tid]);
    }

    // ---- last-block finalize (fused; saves one kernel launch) ----
    __threadfence();   // make this block's bin atomics device-visible
    __shared__ bool is_last;
    if (tid == 0) {
        unsigned prev = atomicAdd((unsigned*)(ws + 2 * NBINS), 1u);
        is_last = (prev == (unsigned)(NBLOCKS - 1));
    }
    __syncthreads();
    if (is_last) {
        __threadfence();   // acquire: see all blocks' bin atomics
        __shared__ float partial[128];
        float t = 0.0f;
        if (tid < NBINS) {
            const int b2 = tid / KB;
            const int k  = (tid % KB) + 1;
            const float kl = ws[tid];
            const float n  = ws[NBINS + tid];
            // Pixel p=0 of image b2 is a corner -> boundary iff gt >= 1.
            // valid = exists boundary pixel with flat index > 0.
            const int k0 = gt[(size_t)b2 * PP];
            const float sub = (k0 == k) ? 1.0f : 0.0f;
            const float npos = n - sub;
            t = (npos > 0.0f) ? (kl / ((float)CC * fmaxf(n, 1.0f))) : 0.0f;
        }
        if (tid < 128) partial[tid] = t;   // NBINS=104 < 128; tids 104..127 write 0
        __syncthreads();
        for (int s = 64; s > 0; s >>= 1) {
            if (tid < s) partial[tid] += partial[tid + s];
            __syncthreads();
        }
        if (tid == 0) out[0] = partial[0];  // LOSS_WEIGHT * TAU^2 = 1
    }
}

extern "C" void kernel_launch(void* const* d_in, const int* in_sizes, int n_in,
                              void* d_out, int out_size, void* d_ws, size_t ws_size,
                              hipStream_t stream) {
    const float* S  = (const float*)d_in[0];
    const float* T  = (const float*)d_in[1];
    const int*   gt = (const int*)d_in[2];
    float* out = (float*)d_out;
    float* ws  = (float*)d_ws;

    hipLaunchKernelGGL(zero_ws_kernel, dim3(1), dim3(256), 0, stream, ws);
    hipLaunchKernelGGL(boundary_kl_kernel, dim3(NBLOCKS), dim3(256), 0, stream,
                       S, T, gt, ws, out);
}